// Round 16
// baseline (474.429 us; speedup 1.0000x reference)
//
#include <hip/hip_runtime.h>
#include <math.h>

typedef unsigned short u16;
typedef __attribute__((ext_vector_type(8))) short bf16x8;   // 8 bf16 (4 VGPRs)
typedef __attribute__((ext_vector_type(4))) float f32x4;
typedef __attribute__((ext_vector_type(16))) float f32x16;

#define Bc   2
#define Lc   2048
#define Hc   1024
#define H6   6144
#define Mc   4096          // B*L
#define LPAD 2050          // padded rows per batch (1 zero row each side)

__device__ __forceinline__ u16 f2b(float f) {
    union { float f; unsigned u; } x; x.f = f;
    unsigned r = x.u + 0x7fffu + ((x.u >> 16) & 1u);
    return (u16)(r >> 16);
}
__device__ __forceinline__ float b2f(u16 h) {
    union { unsigned u; float f; } x; x.u = ((unsigned)h) << 16;
    return x.f;
}
__device__ __forceinline__ void async16(u16* lds, const u16* g) {
    __builtin_amdgcn_global_load_lds((const __attribute__((address_space(1))) void*)g,
                                     (__attribute__((address_space(3))) void*)lds, 16, 0, 0);
}
template<int N> __device__ __forceinline__ void waitcnt_vm() {
    static_assert(N==0 || N==4 || N==10, "literal vmcnt");
    if constexpr (N==0)       asm volatile("s_waitcnt vmcnt(0)" ::: "memory");
    else if constexpr (N==4)  asm volatile("s_waitcnt vmcnt(4)" ::: "memory");
    else                      asm volatile("s_waitcnt vmcnt(10)" ::: "memory");
}
__device__ __forceinline__ float wave_reduce_sum(float v) {
    #pragma unroll
    for (int m = 1; m < 64; m <<= 1) v += __shfl_xor(v, m, 64);
    return v;
}

// ---------------- mod = silu(cond) @ mod_w.T + mod_b (wave per output) ----------
__global__ void mod_kernel(const float* __restrict__ cond, const float* __restrict__ mw,
                           const float* __restrict__ mb, float* __restrict__ mod) {
    __shared__ float sc[Hc];
    int b = blockIdx.y;
    int tid = threadIdx.x;
    for (int i = tid; i < Hc; i += 256) {
        float c = cond[b*Hc + i];
        sc[i] = c / (1.f + __expf(-c));
    }
    __syncthreads();
    int w = tid >> 6, lane = tid & 63;
    int j = blockIdx.x*4 + w;
    const float4* wr = (const float4*)(mw + (size_t)j*Hc);
    const float4* s4 = (const float4*)sc;
    float acc = 0.f;
    #pragma unroll
    for (int i = 0; i < 4; ++i) {
        float4 v = wr[lane + i*64];
        float4 s = s4[lane + i*64];
        acc += v.x*s.x + v.y*s.y + v.z*s.z + v.w*s.w;
    }
    acc = wave_reduce_sum(acc);
    if (lane == 0) mod[b*H6 + j] = acc + mb[j];
}

// ---------------- layernorm(x)*(1+scale)+shift -> bf16 (optionally padded) ------
template<bool PAD>
__global__ void ln_mod_kernel(const float* __restrict__ x, const float* __restrict__ mod,
                              int shoff, int scoff, u16* __restrict__ out) {
    int m = blockIdx.x;
    int b = m >> 11;
    int tid = threadIdx.x;
    float4 v = ((const float4*)(x + (size_t)m*Hc))[tid];
    float s1 = v.x+v.y+v.z+v.w;
    float s2 = v.x*v.x + v.y*v.y + v.z*v.z + v.w*v.w;
    s1 = wave_reduce_sum(s1); s2 = wave_reduce_sum(s2);
    __shared__ float red[8];
    int wid = tid >> 6, lane = tid & 63;
    if (lane == 0) { red[wid] = s1; red[4+wid] = s2; }
    __syncthreads();
    s1 = red[0]+red[1]+red[2]+red[3];
    s2 = red[4]+red[5]+red[6]+red[7];
    float mean = s1 * (1.f/Hc);
    float var  = s2 * (1.f/Hc) - mean*mean;
    float inv  = rsqrtf(var + 1e-5f);
    float4 shv = ((const float4*)(mod + b*H6 + shoff))[tid];
    float4 scv = ((const float4*)(mod + b*H6 + scoff))[tid];
    ushort4 o;
    o.x = f2b((v.x-mean)*inv*(1.f+scv.x)+shv.x);
    o.y = f2b((v.y-mean)*inv*(1.f+scv.y)+shv.y);
    o.z = f2b((v.z-mean)*inv*(1.f+scv.z)+shv.z);
    o.w = f2b((v.w-mean)*inv*(1.f+scv.w)+shv.w);
    size_t row = PAD ? ((size_t)b*LPAD + 1 + (m & 2047)) : (size_t)m;
    ((ushort4*)(out + row*Hc))[tid] = o;
}

// ---------------- weight converters ----------------
__global__ void cvt_plain(const float* __restrict__ src, u16* __restrict__ dst, int n) {
    int i = (blockIdx.x*256 + threadIdx.x)*4;
    if (i < n) {
        float4 v = *(const float4*)(src + i);
        ushort4 o; o.x=f2b(v.x); o.y=f2b(v.y); o.z=f2b(v.z); o.w=f2b(v.w);
        *(ushort4*)(dst + i) = o;
    }
}
// [N][K][3] f32 -> [N][3K] bf16 (K-linearized conv weights), 4 k per thread
__global__ void cvt_conv3(const float* __restrict__ src, u16* __restrict__ dst,
                          int K4, int total) {
    int i = blockIdx.x*256 + threadIdx.x;
    if (i >= total) return;
    int n = i / K4, k4 = (i - n*K4)*4;
    int Kf = K4*4;
    const float4* s4 = (const float4*)(src + ((size_t)n*Kf + k4)*3);
    float4 a = s4[0], b = s4[1], c = s4[2];
    ushort4 t0 = {f2b(a.x), f2b(a.w), f2b(b.z), f2b(c.y)};
    ushort4 t1 = {f2b(a.y), f2b(b.x), f2b(b.w), f2b(c.z)};
    ushort4 t2 = {f2b(a.z), f2b(b.y), f2b(c.x), f2b(c.w)};
    u16* drow = dst + (size_t)n*3*Kf + k4;
    *(ushort4*)(drow)        = t0;
    *(ushort4*)(drow + Kf)   = t1;
    *(ushort4*)(drow + 2*Kf) = t2;
}
__global__ void zero_pads(u16* __restrict__ p, int Kw) {
    int t = blockIdx.x*256 + threadIdx.x;
    if (t >= 4*Kw) return;
    int rr = t / Kw, c = t - rr*Kw;
    int row = (rr >> 1)*2050 + (rr & 1)*2049;   // 0, 2049, 2050, 4099
    p[(size_t)row*Kw + c] = 0;
}

// ---------------- K-linearized MFMA GEMM, 8-wave split-K, N-deep pipeline ------
// C[M,N] = A_eff[M,KEFF] @ W[N,KEFF]^T.  A_eff row m = &Apad[(m-1)*K], stride K.
// R16: wave tile is ALWAYS 64x64 (flop/LDS-byte = Mw*Nw/(Mw+Nw) = 32; R15's
// BM=64/BN=128 had 64x32 waves = 21.3 -> LDS-BW-bound 3.7x, depth couldn't help).
// Configs: BN=128 (BM=128): waves (2m x 2n x 2k), DEPTH=2, 64KB LDS, 2 blk/CU.
//          BN=256 (BM=64, N=1024): waves (4n x 2k), DEPTH=3, 120KB LDS, 1 blk/CU.
// T4 counted vmcnt (R11); split-K merge via LDS (R14); XCD band map (R12).
// EPI: 0 = +bias->bf16 ; 1 = prev+gate*(acc+bias)->f32 ; 2 = plain bf16 ;
//      3 = silu(other)*acc -> bf16 padded
template<int KEFF, bool PADDED, int EPI, int N, int K, int BM, int BN>
__global__ __launch_bounds__(512, 2)
void lgemm(const u16* __restrict__ A, const u16* __restrict__ W,
           const float* __restrict__ bias, const float* __restrict__ prev,
           const u16* __restrict__ other, const float* __restrict__ mod,
           int gate_off, void* __restrict__ Cout)
{
    constexpr int MT  = Mc/BM;
    constexpr int NT  = N/BN;
    constexpr int FI  = 4;                     // 64 rows per wave
    constexpr int FJ  = 4;                     // 64 cols per wave
    constexpr int NPH = KEFF/64;
    constexpr int ACH = BM/64;                 // A stage rounds/lane (2 or 1)
    constexpr int WCH = BN/64;                 // W stage rounds/lane (2 or 4)
    constexpr int LPS = ACH + WCH;             // loads/lane/stage (4 or 5)
    constexpr int DEPTH = (BN == 256) ? 3 : 2;
    constexpr int VMW = (DEPTH - 1) * LPS;     // 4 or 10
    __shared__ __align__(16) u16 ldsbuf[DEPTH*BM*64 + DEPTH*BN*64];

    const int tid = threadIdx.x;
    const int w = tid >> 6, lane = tid & 63;
    const int wk = w >> 2;                                 // K-half owner
    const int wm = (BN == 128) ? ((w >> 1) & 1) : 0;
    const int wn = (BN == 128) ? (w & 1) : (w & 3);
    const int wcol = wn * 64;

    const int orig = blockIdx.x + gridDim.x * blockIdx.y;
    const int xcd = orig & 7, li = orig >> 3;
    const int tm = xcd*(MT/8) + li/NT;         // XCD-private row band
    const int tn = li % NT;                    // n-fastest within band
    const int m0 = tm*BM, n0 = tn*BN;

    const u16* Ab = PADDED ? A + ((size_t)(m0 >> 11)*LPAD + (m0 & 2047))*K
                           : A + (size_t)m0*K;
    const u16* Wb = W + (size_t)n0*KEFF;

    const int lr  = lane >> 3;                 // row within 8-row chunk
    const int lsw = ((lane & 7) ^ lr) * 8;     // pre-swizzled source slot

    const int frow = lane & 15, fsl = lane >> 4;
    const int kslot = wk*4 + fsl;              // this wave's K-half slots

    f32x4 acc[FI][FJ] = {};

#define ASB(buf) (ldsbuf + (buf)*BM*64)
#define WSB(buf) (ldsbuf + DEPTH*BM*64 + (buf)*BN*64)
#define STAGE(t, buf) do {                                                        \
    const int k0_ = (t)*64;                                                       \
    _Pragma("unroll")                                                             \
    for (int i_ = 0; i_ < ACH; ++i_)                                              \
        async16(ASB(buf) + (w + i_*8)*512,                                        \
                Ab + (size_t)((w + i_*8)*8 + lr)*K + k0_ + lsw);                  \
    _Pragma("unroll")                                                             \
    for (int i_ = 0; i_ < WCH; ++i_)                                              \
        async16(WSB(buf) + (w + i_*8)*512,                                        \
                Wb + (size_t)((w + i_*8)*8 + lr)*KEFF + k0_ + lsw);               \
} while (0)

    STAGE(0, 0);
    STAGE(1, 1);
    if (DEPTH == 3) STAGE(2, 2);

    int cur = 0;
    for (int t = 0; t < NPH; ++t) {
        if (t < NPH - 1) waitcnt_vm<VMW>(); else waitcnt_vm<0>();
        __builtin_amdgcn_sched_barrier(0);
        __builtin_amdgcn_s_barrier();              // all waves: cur loads landed
        __builtin_amdgcn_sched_barrier(0);
        bf16x8 a[FI], b[FJ];
        #pragma unroll
        for (int f = 0; f < FI; ++f) {
            const int ar = wm*64 + f*16 + frow;
            a[f] = *(const bf16x8*)&ASB(cur)[ar*64 + ((kslot ^ (ar & 7))*8)];
        }
        #pragma unroll
        for (int f = 0; f < FJ; ++f) {
            const int br = wcol + f*16 + frow;
            b[f] = *(const bf16x8*)&WSB(cur)[br*64 + ((kslot ^ (br & 7))*8)];
        }
        __builtin_amdgcn_sched_barrier(0);
        asm volatile("s_waitcnt lgkmcnt(0)" ::: "memory");
        __builtin_amdgcn_sched_barrier(0);
        __builtin_amdgcn_s_barrier();              // all waves done reading cur
        __builtin_amdgcn_sched_barrier(0);
        if (t + DEPTH < NPH) STAGE(t + DEPTH, cur);  // cur is the free buffer
        __builtin_amdgcn_sched_barrier(0);
        __builtin_amdgcn_s_setprio(1);
        #pragma unroll
        for (int fi = 0; fi < FI; ++fi)
            #pragma unroll
            for (int fj = 0; fj < FJ; ++fj)
                acc[fi][fj] = __builtin_amdgcn_mfma_f32_16x16x32_bf16(
                    a[fi], b[fj], acc[fi][fj], 0, 0, 0);
        __builtin_amdgcn_s_setprio(0);
        cur = (cur == DEPTH - 1) ? 0 : cur + 1;
    }
#undef STAGE

    // ---- split-K merge: wk=1 waves dump acc into (dead) staging LDS ----
    constexpr int PR = FI*FJ*64;               // f32x4 slots per pair
    f32x4* mrg = (f32x4*)ldsbuf;
    __syncthreads();
    if (wk == 1) {
        #pragma unroll
        for (int fi = 0; fi < FI; ++fi)
            #pragma unroll
            for (int fj = 0; fj < FJ; ++fj)
                mrg[(w & 3)*PR + (fi*FJ + fj)*64 + lane] = acc[fi][fj];
    }
    __syncthreads();
    if (wk == 1) return;
    #pragma unroll
    for (int fi = 0; fi < FI; ++fi)
        #pragma unroll
        for (int fj = 0; fj < FJ; ++fj)
            acc[fi][fj] += mrg[(w & 3)*PR + (fi*FJ + fj)*64 + lane];

    // epilogue: D row=(lane>>4)*4+reg, col=lane&15  [verified m89]
    #pragma unroll
    for (int fi = 0; fi < FI; ++fi) {
        #pragma unroll
        for (int i = 0; i < 4; ++i) {
            const int gm = m0 + wm*64 + fi*16 + (lane >> 4)*4 + i;
            const int bb = gm >> 11;
            #pragma unroll
            for (int fj = 0; fj < FJ; ++fj) {
                const int col = n0 + wcol + fj*16 + frow;
                float r = acc[fi][fj][i];
                if (EPI == 0) {
                    ((u16*)Cout)[(size_t)gm*N + col] = f2b(r + bias[col]);
                } else if (EPI == 1) {
                    if (bias) r += bias[col];
                    const float g = mod[bb*H6 + gate_off + col];
                    ((float*)Cout)[(size_t)gm*N + col] =
                        prev[(size_t)gm*N + col] + g*r;
                } else if (EPI == 2) {
                    ((u16*)Cout)[(size_t)gm*N + col] = f2b(r);
                } else {
                    const float h = b2f(other[(size_t)gm*N + col]);
                    const float v = h / (1.f + __expf(-h)) * r;
                    ((u16*)Cout)[((size_t)bb*LPAD + 1 + (gm & 2047))*N + col] = f2b(v);
                }
            }
        }
    }
#undef ASB
#undef WSB
}

// ---------------- RMSNorm + RoPE + split qkv (bf16 in/out; Q pre-scaled) --------
__global__ void rope_rms(const u16* __restrict__ qkv,
                         const float* __restrict__ qn_w, const float* __restrict__ kn_w,
                         const float* __restrict__ fcos, const float* __restrict__ fsin,
                         u16* __restrict__ Q, u16* __restrict__ K, u16* __restrict__ V) {
    int bh = blockIdx.y;
    int l  = blockIdx.x*4 + (threadIdx.x >> 6);
    int d  = threadIdx.x & 63;
    int b  = bh >> 4, h = bh & 15;
    size_t base = ((size_t)(b*Lc + l))*3072 + (size_t)(h*64 + d)*3;
    float qv = b2f(qkv[base + 0]);
    float kv = b2f(qkv[base + 1]);
    float vv = b2f(qkv[base + 2]);
    float qs = wave_reduce_sum(qv*qv) * (1.f/64.f);
    float ks = wave_reduce_sum(kv*kv) * (1.f/64.f);
    float qn = qv * rsqrtf(qs + 1e-6f) * qn_w[d];
    float kn = kv * rsqrtf(ks + 1e-6f) * kn_w[d];
    float c = fcos[l*64 + d], s = fsin[l*64 + d];
    float qp = __shfl_xor(qn, 1, 64);
    float kp = __shfl_xor(kn, 1, 64);
    float qr = (d & 1) ? qp : -qp;
    float kr = (d & 1) ? kp : -kp;
    size_t o = ((size_t)bh*Lc + l)*64 + d;
    Q[o] = f2b((qn*c + qr*s) * 0.125f);     // fold 1/sqrt(D) into Q
    K[o] = f2b(kn*c + kr*s);
    V[o] = f2b(vv);
}

// ---------------- V transpose: [bh][l][64] -> [bh][64][l] ----------------
__global__ void vtrans(const u16* __restrict__ V, u16* __restrict__ Vt) {
    __shared__ u16 t[64][65];
    int bh = blockIdx.y, l0 = blockIdx.x*64;
    int tid = threadIdx.x;
    #pragma unroll
    for (int p = 0; p < 16; ++p) {
        int idx = p*256 + tid; int r = idx >> 6, c = idx & 63;
        t[r][c] = V[((size_t)bh*Lc + l0 + r)*64 + c];
    }
    __syncthreads();
    #pragma unroll
    for (int p = 0; p < 16; ++p) {
        int idx = p*256 + tid; int d = idx >> 6, c = idx & 63;
        Vt[((size_t)bh*64 + d)*Lc + l0 + c] = t[c][d];
    }
}

// ---------------- flash attention: 32x32 MFMA, in-register softmax ----------
#define PV_STEP(c, SV) do {                                                        \
    unsigned cA,cB,cC,cD;                                                          \
    asm("v_cvt_pk_bf16_f32 %0,%1,%2" : "=v"(cA) : "v"(SV[((c)&1)*8+0]), "v"(SV[((c)&1)*8+1])); \
    asm("v_cvt_pk_bf16_f32 %0,%1,%2" : "=v"(cB) : "v"(SV[((c)&1)*8+2]), "v"(SV[((c)&1)*8+3])); \
    asm("v_cvt_pk_bf16_f32 %0,%1,%2" : "=v"(cC) : "v"(SV[((c)&1)*8+4]), "v"(SV[((c)&1)*8+5])); \
    asm("v_cvt_pk_bf16_f32 %0,%1,%2" : "=v"(cD) : "v"(SV[((c)&1)*8+6]), "v"(SV[((c)&1)*8+7])); \
    asm("v_permlane32_swap_b32 %0, %1" : "+v"(cA), "+v"(cC));                      \
    asm("v_permlane32_swap_b32 %0, %1" : "+v"(cB), "+v"(cD));                      \
    union { unsigned u[4]; bf16x8 v; } pa_;                                        \
    pa_.u[0]=cA; pa_.u[1]=cB; pa_.u[2]=cC; pa_.u[3]=cD;                            \
    const int slot_ = (c)*2 + g;                                                   \
    bf16x8 vA = *(const bf16x8*)&Vs[cur][q31*64 + ((slot_ ^ (q31 & 7))*8)];        \
    bf16x8 vB = *(const bf16x8*)&Vs[cur][(32+q31)*64 + ((slot_ ^ (q31 & 7))*8)];   \
    o0 = __builtin_amdgcn_mfma_f32_32x32x16_bf16(pa_.v, vA, o0, 0,0,0);            \
    o1 = __builtin_amdgcn_mfma_f32_32x32x16_bf16(pa_.v, vB, o1, 0,0,0);            \
} while(0)

__global__ __launch_bounds__(256, 2)
void attn_kernel(const u16* __restrict__ Q, const u16* __restrict__ K,
                 const u16* __restrict__ Vt, u16* __restrict__ Opad)
{
    __shared__ u16 Ks[2][4096];
    __shared__ u16 Vs[2][4096];
    __shared__ float lred[4][32];
    const int tid = threadIdx.x;
    const int w = tid >> 6, lane = tid & 63;
    const int q31 = lane & 31, g = lane >> 5;
    const int bh = blockIdx.y;
    const int q0 = blockIdx.x*128 + w*32;
    const u16* Qb = Q  + (size_t)bh*Lc*64;
    const u16* Kb = K  + (size_t)bh*Lc*64;
    const u16* Vb = Vt + (size_t)bh*Lc*64;   // [64 d][2048 kv]

    bf16x8 qf[4];
    #pragma unroll
    for (int st = 0; st < 4; ++st)
        qf[st] = *(const bf16x8*)&Qb[(size_t)(q0 + q31)*64 + st*16 + g*8];

    f32x16 o0 = {}, o1 = {};
    float m_ = -1e30f, l_ = 0.f;

    const int sr = lane >> 3;
    const int sg = ((lane & 7) ^ sr) * 8;

    #pragma unroll
    for (int i = 0; i < 2; ++i) {
        const int c = w + i*4;
        async16(&Ks[0][c*512], Kb + (size_t)(c*8 + sr)*64 + sg);
        async16(&Vs[0][c*512], Vb + (size_t)(c*8 + sr)*Lc + sg);
    }
    __syncthreads();

    int cur = 0;
    for (int kv0 = 0; kv0 < Lc; kv0 += 64) {
        if (kv0 + 64 < Lc) {
            #pragma unroll
            for (int i = 0; i < 2; ++i) {
                const int c = w + i*4;
                async16(&Ks[cur^1][c*512], Kb + (size_t)(kv0 + 64 + c*8 + sr)*64 + sg);
                async16(&Vs[cur^1][c*512], Vb + (size_t)(c*8 + sr)*Lc + kv0 + 64 + sg);
            }
        }
        f32x16 s0 = {}, s1 = {};
        __builtin_amdgcn_s_setprio(1);
        #pragma unroll
        for (int st = 0; st < 4; ++st) {
            const int slot = st*2 + g;
            bf16x8 ka0 = *(const bf16x8*)&Ks[cur][q31*64 + ((slot ^ (q31 & 7))*8)];
            bf16x8 ka1 = *(const bf16x8*)&Ks[cur][(32+q31)*64 + ((slot ^ (q31 & 7))*8)];
            s0 = __builtin_amdgcn_mfma_f32_32x32x16_bf16(ka0, qf[st], s0, 0,0,0);
            s1 = __builtin_amdgcn_mfma_f32_32x32x16_bf16(ka1, qf[st], s1, 0,0,0);
        }
        __builtin_amdgcn_s_setprio(0);
        float pmax = s0[0];
        #pragma unroll
        for (int r = 1; r < 16; ++r) pmax = fmaxf(pmax, s0[r]);
        #pragma unroll
        for (int r = 0; r < 16; ++r) pmax = fmaxf(pmax, s1[r]);
        pmax = fmaxf(pmax, __shfl_xor(pmax, 32, 64));
        if (!__all(pmax <= m_ + 8.f)) {
            const float mn = fmaxf(m_, pmax);
            const float al = __expf(m_ - mn);
            m_ = mn; l_ *= al;
            #pragma unroll
            for (int r = 0; r < 16; ++r) { o0[r] *= al; o1[r] *= al; }
        }
        #pragma unroll
        for (int r = 0; r < 16; ++r) {
            const float p0 = __expf(s0[r] - m_); s0[r] = p0; l_ += p0;
            const float p1 = __expf(s1[r] - m_); s1[r] = p1; l_ += p1;
        }
        __builtin_amdgcn_s_setprio(1);
        PV_STEP(0, s0); PV_STEP(1, s0); PV_STEP(2, s1); PV_STEP(3, s1);
        __builtin_amdgcn_s_setprio(0);
        __syncthreads();
        cur ^= 1;
    }

    const float lt = l_ + __shfl_xor(l_, 32, 64);
    if (g == 0) lred[w][q31] = lt;
    __syncthreads();
    const int b = bh >> 4, h = bh & 15;
    #pragma unroll
    for (int r = 0; r < 16; ++r) {
        const int ql = (r & 3) + 8*(r >> 2) + 4*g;
        const float inv = 1.f / lred[w][ql];
        const size_t prow = (size_t)b*LPAD + 1 + (q0 + ql);
        Opad[prow*Hc + h*64 + q31]      = f2b(o0[r]*inv);
        Opad[prow*Hc + h*64 + 32 + q31] = f2b(o1[r]*inv);
    }
}

extern "C" void kernel_launch(void* const* d_in, const int* in_sizes, int n_in,
                              void* d_out, int out_size, void* d_ws, size_t ws_size,
                              hipStream_t stream) {
    const float* x      = (const float*)d_in[0];
    const float* cond   = (const float*)d_in[1];
    const float* fcos   = (const float*)d_in[2];
    const float* fsin   = (const float*)d_in[3];
    const float* mod_w  = (const float*)d_in[4];
    const float* mod_b  = (const float*)d_in[5];
    const float* qkv_w  = (const float*)d_in[6];
    const float* qkv_b  = (const float*)d_in[7];
    const float* qn_w   = (const float*)d_in[8];
    const float* kn_w   = (const float*)d_in[9];
    const float* lin1_w = (const float*)d_in[10];
    const float* lin1_b = (const float*)d_in[11];
    const float* w1     = (const float*)d_in[12];
    const float* w2     = (const float*)d_in[13];
    const float* w3     = (const float*)d_in[14];
    float* out = (float*)d_out;
    char* wsb  = (char*)d_ws;

    float* mod  = (float*)(wsb + 0);                       // 48 KB
    u16* Wslot  = (u16*)(wsb + (1u<<20));                  // <=17.3 MiB, reused
    u16* Breg   = (u16*)(wsb + 19u*1024*1024);             // xn1 -> attn_pad
    u16* Creg   = (u16*)(wsb + 28u*1024*1024);             // qkvb -> h1a
    u16* Dreg   = (u16*)(wsb + 54u*1024*1024);             // Q,K,V,Vt -> xn2_pad
    u16* Ereg   = (u16*)(wsb + 88u*1024*1024);             // h1_pad

    u16* xn1  = Breg;
    u16* apad = Breg;
    u16* qkvb = Creg;
    u16* h1a  = Creg;       // reuse after qkvb is dead (post rope_rms)
    u16* Qb = Dreg;
    u16* Kb = Dreg + 4194304;
    u16* Vb = Dreg + 8388608;
    u16* Vt = Dreg + 12582912;
    u16* xn2p = Dreg;
    u16* h1p  = Ereg;

    dim3 blk(256), blkg(512);
    mod_kernel<<<dim3(H6/4, Bc), blk, 0, stream>>>(cond, mod_w, mod_b, mod);
    zero_pads<<<dim3((4*2816 + 255)/256), blk, 0, stream>>>(h1p, 2816);
    ln_mod_kernel<false><<<Mc, blk, 0, stream>>>(x, mod, 0, Hc, xn1);
    cvt_plain<<<dim3((3072*1024/4 + 255)/256), blk, 0, stream>>>(qkv_w, Wslot, 3072*1024);
    lgemm<1024,false,0,3072,1024,128,128><<<dim3(24,32), blkg, 0, stream>>>(
        xn1, Wslot, qkv_b, nullptr, nullptr, nullptr, 0, qkvb);
    zero_pads<<<dim3((4*1024 + 255)/256), blk, 0, stream>>>(apad, 1024);   // xn1 dead now
    rope_rms<<<dim3(Lc/4, 32), blk, 0, stream>>>(qkvb, qn_w, kn_w, fcos, fsin, Qb, Kb, Vb);
    vtrans<<<dim3(32, 32), blk, 0, stream>>>(Vb, Vt);
    attn_kernel<<<dim3(16, 32), blk, 0, stream>>>(Qb, Kb, Vt, apad);
    cvt_conv3<<<dim3((1024*256 + 255)/256), blk, 0, stream>>>(lin1_w, Wslot, 256, 1024*256);
    lgemm<3072,true,1,1024,1024,64,256><<<dim3(4,64), blkg, 0, stream>>>(
        apad, Wslot, lin1_b, x, nullptr, mod, 2*Hc, (void*)out);
    zero_pads<<<dim3((4*1024 + 255)/256), blk, 0, stream>>>(xn2p, 1024);   // Q..Vt dead now
    ln_mod_kernel<true><<<Mc, blk, 0, stream>>>(out, mod, 3*Hc, 4*Hc, xn2p);
    cvt_conv3<<<dim3((2816*256 + 255)/256), blk, 0, stream>>>(w1, Wslot, 256, 2816*256);
    lgemm<3072,true,2,2816,1024,128,128><<<dim3(22,32), blkg, 0, stream>>>(
        xn2p, Wslot, nullptr, nullptr, nullptr, nullptr, 0, h1a);
    cvt_conv3<<<dim3((2816*256 + 255)/256), blk, 0, stream>>>(w3, Wslot, 256, 2816*256);
    lgemm<3072,true,3,2816,1024,128,128><<<dim3(22,32), blkg, 0, stream>>>(
        xn2p, Wslot, nullptr, nullptr, h1a, nullptr, 0, h1p);
    cvt_conv3<<<dim3((1024*704 + 255)/256), blk, 0, stream>>>(w2, Wslot, 704, 1024*704);
    lgemm<8448,true,1,1024,2816,64,256><<<dim3(4,64), blkg, 0, stream>>>(
        h1p, Wslot, nullptr, out, nullptr, mod, 5*Hc, (void*)out);
    (void)in_sizes; (void)n_in; (void)out_size; (void)ws_size;
}

// Round 17
// 449.772 us; speedup vs baseline: 1.0548x; 1.0548x over previous
//
#include <hip/hip_runtime.h>
#include <math.h>

typedef unsigned short u16;
typedef __attribute__((ext_vector_type(8))) short bf16x8;   // 8 bf16 (4 VGPRs)
typedef __attribute__((ext_vector_type(4))) float f32x4;
typedef __attribute__((ext_vector_type(16))) float f32x16;

#define Bc   2
#define Lc   2048
#define Hc   1024
#define H6   6144
#define Mc   4096          // B*L
#define LPAD 2050          // padded rows per batch (1 zero row each side)

__device__ __forceinline__ u16 f2b(float f) {
    union { float f; unsigned u; } x; x.f = f;
    unsigned r = x.u + 0x7fffu + ((x.u >> 16) & 1u);
    return (u16)(r >> 16);
}
__device__ __forceinline__ float b2f(u16 h) {
    union { unsigned u; float f; } x; x.u = ((unsigned)h) << 16;
    return x.f;
}
__device__ __forceinline__ void async16(u16* lds, const u16* g) {
    __builtin_amdgcn_global_load_lds((const __attribute__((address_space(1))) void*)g,
                                     (__attribute__((address_space(3))) void*)lds, 16, 0, 0);
}
template<int N> __device__ __forceinline__ void waitcnt_vm() {
    static_assert(N==0 || N==3 || N==4, "literal vmcnt");
    if constexpr (N==0)      asm volatile("s_waitcnt vmcnt(0)" ::: "memory");
    else if constexpr (N==3) asm volatile("s_waitcnt vmcnt(3)" ::: "memory");
    else                     asm volatile("s_waitcnt vmcnt(4)" ::: "memory");
}
__device__ __forceinline__ float wave_reduce_sum(float v) {
    #pragma unroll
    for (int m = 1; m < 64; m <<= 1) v += __shfl_xor(v, m, 64);
    return v;
}

// ---------------- mod = silu(cond) @ mod_w.T + mod_b (wave per output) ----------
__global__ void mod_kernel(const float* __restrict__ cond, const float* __restrict__ mw,
                           const float* __restrict__ mb, float* __restrict__ mod) {
    __shared__ float sc[Hc];
    int b = blockIdx.y;
    int tid = threadIdx.x;
    for (int i = tid; i < Hc; i += 256) {
        float c = cond[b*Hc + i];
        sc[i] = c / (1.f + __expf(-c));
    }
    __syncthreads();
    int w = tid >> 6, lane = tid & 63;
    int j = blockIdx.x*4 + w;
    const float4* wr = (const float4*)(mw + (size_t)j*Hc);
    const float4* s4 = (const float4*)sc;
    float acc = 0.f;
    #pragma unroll
    for (int i = 0; i < 4; ++i) {
        float4 v = wr[lane + i*64];
        float4 s = s4[lane + i*64];
        acc += v.x*s.x + v.y*s.y + v.z*s.z + v.w*s.w;
    }
    acc = wave_reduce_sum(acc);
    if (lane == 0) mod[b*H6 + j] = acc + mb[j];
}

// ---------------- layernorm(x)*(1+scale)+shift -> bf16 (optionally padded) ------
template<bool PAD>
__global__ void ln_mod_kernel(const float* __restrict__ x, const float* __restrict__ mod,
                              int shoff, int scoff, u16* __restrict__ out) {
    int m = blockIdx.x;
    int b = m >> 11;
    int tid = threadIdx.x;
    float4 v = ((const float4*)(x + (size_t)m*Hc))[tid];
    float s1 = v.x+v.y+v.z+v.w;
    float s2 = v.x*v.x + v.y*v.y + v.z*v.z + v.w*v.w;
    s1 = wave_reduce_sum(s1); s2 = wave_reduce_sum(s2);
    __shared__ float red[8];
    int wid = tid >> 6, lane = tid & 63;
    if (lane == 0) { red[wid] = s1; red[4+wid] = s2; }
    __syncthreads();
    s1 = red[0]+red[1]+red[2]+red[3];
    s2 = red[4]+red[5]+red[6]+red[7];
    float mean = s1 * (1.f/Hc);
    float var  = s2 * (1.f/Hc) - mean*mean;
    float inv  = rsqrtf(var + 1e-5f);
    float4 shv = ((const float4*)(mod + b*H6 + shoff))[tid];
    float4 scv = ((const float4*)(mod + b*H6 + scoff))[tid];
    ushort4 o;
    o.x = f2b((v.x-mean)*inv*(1.f+scv.x)+shv.x);
    o.y = f2b((v.y-mean)*inv*(1.f+scv.y)+shv.y);
    o.z = f2b((v.z-mean)*inv*(1.f+scv.z)+shv.z);
    o.w = f2b((v.w-mean)*inv*(1.f+scv.w)+shv.w);
    size_t row = PAD ? ((size_t)b*LPAD + 1 + (m & 2047)) : (size_t)m;
    ((ushort4*)(out + row*Hc))[tid] = o;
}

// ---------------- weight converters ----------------
__global__ void cvt_plain(const float* __restrict__ src, u16* __restrict__ dst, int n) {
    int i = (blockIdx.x*256 + threadIdx.x)*4;
    if (i < n) {
        float4 v = *(const float4*)(src + i);
        ushort4 o; o.x=f2b(v.x); o.y=f2b(v.y); o.z=f2b(v.z); o.w=f2b(v.w);
        *(ushort4*)(dst + i) = o;
    }
}
// [N][K][3] f32 -> [N][3K] bf16 (K-linearized conv weights), 4 k per thread
__global__ void cvt_conv3(const float* __restrict__ src, u16* __restrict__ dst,
                          int K4, int total) {
    int i = blockIdx.x*256 + threadIdx.x;
    if (i >= total) return;
    int n = i / K4, k4 = (i - n*K4)*4;
    int Kf = K4*4;
    const float4* s4 = (const float4*)(src + ((size_t)n*Kf + k4)*3);
    float4 a = s4[0], b = s4[1], c = s4[2];
    ushort4 t0 = {f2b(a.x), f2b(a.w), f2b(b.z), f2b(c.y)};
    ushort4 t1 = {f2b(a.y), f2b(b.x), f2b(b.w), f2b(c.z)};
    ushort4 t2 = {f2b(a.z), f2b(b.y), f2b(c.x), f2b(c.w)};
    u16* drow = dst + (size_t)n*3*Kf + k4;
    *(ushort4*)(drow)        = t0;
    *(ushort4*)(drow + Kf)   = t1;
    *(ushort4*)(drow + 2*Kf) = t2;
}
__global__ void zero_pads(u16* __restrict__ p, int Kw) {
    int t = blockIdx.x*256 + threadIdx.x;
    if (t >= 4*Kw) return;
    int rr = t / Kw, c = t - rr*Kw;
    int row = (rr >> 1)*2050 + (rr & 1)*2049;   // 0, 2049, 2050, 4099
    p[(size_t)row*Kw + c] = 0;
}

// ---------------- K-linearized MFMA GEMM, 8-wave split-K, counted-vmcnt --------
// C[M,N] = A_eff[M,KEFF] @ W[N,KEFF]^T.  A_eff row m = &Apad[(m-1)*K], stride K.
// R17 = exact R14 config (best measured: 452us total). Split-K across waves:
// wave grid (2m x 2n x 2k) for BM=128, (1m x 4n x 2k) for BM=64; merge via LDS.
// 2-deep counted-vmcnt pipeline (R11); XCD band map (R12, FETCH 287->110MB).
// R15 (DEPTH=3) was null; R16 (BN=256, 1 blk/CU) regressed +22us — both reverted.
// EPI: 0 = +bias->bf16 ; 1 = prev+gate*(acc+bias)->f32 ; 2 = plain bf16 ;
//      3 = silu(other)*acc -> bf16 padded
template<int KEFF, bool PADDED, int EPI, int N, int K, int BM>
__global__ __launch_bounds__(512, 2)
void lgemm(const u16* __restrict__ A, const u16* __restrict__ W,
           const float* __restrict__ bias, const float* __restrict__ prev,
           const u16* __restrict__ other, const float* __restrict__ mod,
           int gate_off, void* __restrict__ Cout)
{
    constexpr int MT  = Mc/BM;
    constexpr int NT  = N/128;
    constexpr int FI  = 4;                     // 64 rows per wave
    constexpr int FJ  = (BM == 128) ? 4 : 2;   // 64 / 32 cols per wave
    constexpr int NPH = KEFF/64;
    constexpr int ACH = BM/64;                 // A stage rounds per lane (2 or 1)
    constexpr int LPS = ACH + 2;               // loads/lane/stage (4 or 3)
    __shared__ __align__(16) u16 ldsbuf[2*BM*64 + 2*128*64];

    const int tid = threadIdx.x;
    const int w = tid >> 6, lane = tid & 63;
    const int wk = w >> 2;                                 // K-half owner
    const int wm = (BM == 128) ? ((w >> 1) & 1) : 0;
    const int wn = (BM == 128) ? (w & 1) : (w & 3);
    const int wcol = wn * (128/((BM == 128) ? 2 : 4));     // 64 or 32

    const int orig = blockIdx.x + gridDim.x * blockIdx.y;
    const int xcd = orig & 7, li = orig >> 3;
    const int tm = xcd*(MT/8) + li/NT;         // XCD-private row band
    const int tn = li % NT;                    // n-fastest within band
    const int m0 = tm*BM, n0 = tn*128;

    const u16* Ab = PADDED ? A + ((size_t)(m0 >> 11)*LPAD + (m0 & 2047))*K
                           : A + (size_t)m0*K;
    const u16* Wb = W + (size_t)n0*KEFF;

    const int lr  = lane >> 3;                 // row within 8-row chunk
    const int lsw = ((lane & 7) ^ lr) * 8;     // pre-swizzled source slot

    const int frow = lane & 15, fsl = lane >> 4;
    const int kslot = wk*4 + fsl;              // this wave's K-half slots

    f32x4 acc[FI][FJ] = {};

#define ASB(buf) (ldsbuf + (buf)*BM*64)
#define WSB(buf) (ldsbuf + 2*BM*64 + (buf)*128*64)
#define STAGE(t, buf) do {                                                        \
    const int k0_ = (t)*64;                                                       \
    _Pragma("unroll")                                                             \
    for (int i_ = 0; i_ < ACH; ++i_)                                              \
        async16(ASB(buf) + (w + i_*8)*512,                                        \
                Ab + (size_t)((w + i_*8)*8 + lr)*K + k0_ + lsw);                  \
    _Pragma("unroll")                                                             \
    for (int i_ = 0; i_ < 2; ++i_)                                                \
        async16(WSB(buf) + (w + i_*8)*512,                                        \
                Wb + (size_t)((w + i_*8)*8 + lr)*KEFF + k0_ + lsw);               \
} while (0)

    STAGE(0, 0);
    STAGE(1, 1);

    for (int t = 0; t < NPH; ++t) {
        const int cur = t & 1;
        if (t < NPH - 1) waitcnt_vm<LPS>(); else waitcnt_vm<0>();
        __builtin_amdgcn_sched_barrier(0);
        __builtin_amdgcn_s_barrier();              // all waves: cur loads landed
        __builtin_amdgcn_sched_barrier(0);
        bf16x8 a[FI], b[FJ];
        #pragma unroll
        for (int f = 0; f < FI; ++f) {
            const int ar = wm*64 + f*16 + frow;
            a[f] = *(const bf16x8*)&ASB(cur)[ar*64 + ((kslot ^ (ar & 7))*8)];
        }
        #pragma unroll
        for (int f = 0; f < FJ; ++f) {
            const int br = wcol + f*16 + frow;
            b[f] = *(const bf16x8*)&WSB(cur)[br*64 + ((kslot ^ (br & 7))*8)];
        }
        __builtin_amdgcn_sched_barrier(0);
        asm volatile("s_waitcnt lgkmcnt(0)" ::: "memory");
        __builtin_amdgcn_sched_barrier(0);
        __builtin_amdgcn_s_barrier();              // all waves done reading cur
        __builtin_amdgcn_sched_barrier(0);
        if (t + 2 < NPH) STAGE(t + 2, cur);        // overwrite cur for t+2
        __builtin_amdgcn_sched_barrier(0);
        __builtin_amdgcn_s_setprio(1);
        #pragma unroll
        for (int fi = 0; fi < FI; ++fi)
            #pragma unroll
            for (int fj = 0; fj < FJ; ++fj)
                acc[fi][fj] = __builtin_amdgcn_mfma_f32_16x16x32_bf16(
                    a[fi], b[fj], acc[fi][fj], 0, 0, 0);
        __builtin_amdgcn_s_setprio(0);
    }
#undef STAGE

    // ---- split-K merge: wk=1 waves dump acc into (dead) staging LDS ----
    constexpr int PR = FI*FJ*64;               // f32x4 slots per pair
    f32x4* mrg = (f32x4*)ldsbuf;
    __syncthreads();
    if (wk == 1) {
        #pragma unroll
        for (int fi = 0; fi < FI; ++fi)
            #pragma unroll
            for (int fj = 0; fj < FJ; ++fj)
                mrg[(w & 3)*PR + (fi*FJ + fj)*64 + lane] = acc[fi][fj];
    }
    __syncthreads();
    if (wk == 1) return;
    #pragma unroll
    for (int fi = 0; fi < FI; ++fi)
        #pragma unroll
        for (int fj = 0; fj < FJ; ++fj)
            acc[fi][fj] += mrg[(w & 3)*PR + (fi*FJ + fj)*64 + lane];

    // epilogue: D row=(lane>>4)*4+reg, col=lane&15  [verified m89]
    #pragma unroll
    for (int fi = 0; fi < FI; ++fi) {
        #pragma unroll
        for (int i = 0; i < 4; ++i) {
            const int gm = m0 + wm*64 + fi*16 + (lane >> 4)*4 + i;
            const int bb = gm >> 11;
            #pragma unroll
            for (int fj = 0; fj < FJ; ++fj) {
                const int col = n0 + wcol + fj*16 + frow;
                float r = acc[fi][fj][i];
                if (EPI == 0) {
                    ((u16*)Cout)[(size_t)gm*N + col] = f2b(r + bias[col]);
                } else if (EPI == 1) {
                    if (bias) r += bias[col];
                    const float g = mod[bb*H6 + gate_off + col];
                    ((float*)Cout)[(size_t)gm*N + col] =
                        prev[(size_t)gm*N + col] + g*r;
                } else if (EPI == 2) {
                    ((u16*)Cout)[(size_t)gm*N + col] = f2b(r);
                } else {
                    const float h = b2f(other[(size_t)gm*N + col]);
                    const float v = h / (1.f + __expf(-h)) * r;
                    ((u16*)Cout)[((size_t)bb*LPAD + 1 + (gm & 2047))*N + col] = f2b(v);
                }
            }
        }
    }
#undef ASB
#undef WSB
}

// ---------------- RMSNorm + RoPE + split qkv (bf16 in/out; Q pre-scaled) --------
__global__ void rope_rms(const u16* __restrict__ qkv,
                         const float* __restrict__ qn_w, const float* __restrict__ kn_w,
                         const float* __restrict__ fcos, const float* __restrict__ fsin,
                         u16* __restrict__ Q, u16* __restrict__ K, u16* __restrict__ V) {
    int bh = blockIdx.y;
    int l  = blockIdx.x*4 + (threadIdx.x >> 6);
    int d  = threadIdx.x & 63;
    int b  = bh >> 4, h = bh & 15;
    size_t base = ((size_t)(b*Lc + l))*3072 + (size_t)(h*64 + d)*3;
    float qv = b2f(qkv[base + 0]);
    float kv = b2f(qkv[base + 1]);
    float vv = b2f(qkv[base + 2]);
    float qs = wave_reduce_sum(qv*qv) * (1.f/64.f);
    float ks = wave_reduce_sum(kv*kv) * (1.f/64.f);
    float qn = qv * rsqrtf(qs + 1e-6f) * qn_w[d];
    float kn = kv * rsqrtf(ks + 1e-6f) * kn_w[d];
    float c = fcos[l*64 + d], s = fsin[l*64 + d];
    float qp = __shfl_xor(qn, 1, 64);
    float kp = __shfl_xor(kn, 1, 64);
    float qr = (d & 1) ? qp : -qp;
    float kr = (d & 1) ? kp : -kp;
    size_t o = ((size_t)bh*Lc + l)*64 + d;
    Q[o] = f2b((qn*c + qr*s) * 0.125f);     // fold 1/sqrt(D) into Q
    K[o] = f2b(kn*c + kr*s);
    V[o] = f2b(vv);
}

// ---------------- V transpose: [bh][l][64] -> [bh][64][l] ----------------
__global__ void vtrans(const u16* __restrict__ V, u16* __restrict__ Vt) {
    __shared__ u16 t[64][65];
    int bh = blockIdx.y, l0 = blockIdx.x*64;
    int tid = threadIdx.x;
    #pragma unroll
    for (int p = 0; p < 16; ++p) {
        int idx = p*256 + tid; int r = idx >> 6, c = idx & 63;
        t[r][c] = V[((size_t)bh*Lc + l0 + r)*64 + c];
    }
    __syncthreads();
    #pragma unroll
    for (int p = 0; p < 16; ++p) {
        int idx = p*256 + tid; int d = idx >> 6, c = idx & 63;
        Vt[((size_t)bh*64 + d)*Lc + l0 + c] = t[c][d];
    }
}

// ---------------- flash attention: 32x32 MFMA, in-register softmax ----------
#define PV_STEP(c, SV) do {                                                        \
    unsigned cA,cB,cC,cD;                                                          \
    asm("v_cvt_pk_bf16_f32 %0,%1,%2" : "=v"(cA) : "v"(SV[((c)&1)*8+0]), "v"(SV[((c)&1)*8+1])); \
    asm("v_cvt_pk_bf16_f32 %0,%1,%2" : "=v"(cB) : "v"(SV[((c)&1)*8+2]), "v"(SV[((c)&1)*8+3])); \
    asm("v_cvt_pk_bf16_f32 %0,%1,%2" : "=v"(cC) : "v"(SV[((c)&1)*8+4]), "v"(SV[((c)&1)*8+5])); \
    asm("v_cvt_pk_bf16_f32 %0,%1,%2" : "=v"(cD) : "v"(SV[((c)&1)*8+6]), "v"(SV[((c)&1)*8+7])); \
    asm("v_permlane32_swap_b32 %0, %1" : "+v"(cA), "+v"(cC));                      \
    asm("v_permlane32_swap_b32 %0, %1" : "+v"(cB), "+v"(cD));                      \
    union { unsigned u[4]; bf16x8 v; } pa_;                                        \
    pa_.u[0]=cA; pa_.u[1]=cB; pa_.u[2]=cC; pa_.u[3]=cD;                            \
    const int slot_ = (c)*2 + g;                                                   \
    bf16x8 vA = *(const bf16x8*)&Vs[cur][q31*64 + ((slot_ ^ (q31 & 7))*8)];        \
    bf16x8 vB = *(const bf16x8*)&Vs[cur][(32+q31)*64 + ((slot_ ^ (q31 & 7))*8)];   \
    o0 = __builtin_amdgcn_mfma_f32_32x32x16_bf16(pa_.v, vA, o0, 0,0,0);            \
    o1 = __builtin_amdgcn_mfma_f32_32x32x16_bf16(pa_.v, vB, o1, 0,0,0);            \
} while(0)

__global__ __launch_bounds__(256, 2)
void attn_kernel(const u16* __restrict__ Q, const u16* __restrict__ K,
                 const u16* __restrict__ Vt, u16* __restrict__ Opad)
{
    __shared__ u16 Ks[2][4096];
    __shared__ u16 Vs[2][4096];
    __shared__ float lred[4][32];
    const int tid = threadIdx.x;
    const int w = tid >> 6, lane = tid & 63;
    const int q31 = lane & 31, g = lane >> 5;
    const int bh = blockIdx.y;
    const int q0 = blockIdx.x*128 + w*32;
    const u16* Qb = Q  + (size_t)bh*Lc*64;
    const u16* Kb = K  + (size_t)bh*Lc*64;
    const u16* Vb = Vt + (size_t)bh*Lc*64;   // [64 d][2048 kv]

    bf16x8 qf[4];
    #pragma unroll
    for (int st = 0; st < 4; ++st)
        qf[st] = *(const bf16x8*)&Qb[(size_t)(q0 + q31)*64 + st*16 + g*8];

    f32x16 o0 = {}, o1 = {};
    float m_ = -1e30f, l_ = 0.f;

    const int sr = lane >> 3;
    const int sg = ((lane & 7) ^ sr) * 8;

    #pragma unroll
    for (int i = 0; i < 2; ++i) {
        const int c = w + i*4;
        async16(&Ks[0][c*512], Kb + (size_t)(c*8 + sr)*64 + sg);
        async16(&Vs[0][c*512], Vb + (size_t)(c*8 + sr)*Lc + sg);
    }
    __syncthreads();

    int cur = 0;
    for (int kv0 = 0; kv0 < Lc; kv0 += 64) {
        if (kv0 + 64 < Lc) {
            #pragma unroll
            for (int i = 0; i < 2; ++i) {
                const int c = w + i*4;
                async16(&Ks[cur^1][c*512], Kb + (size_t)(kv0 + 64 + c*8 + sr)*64 + sg);
                async16(&Vs[cur^1][c*512], Vb + (size_t)(c*8 + sr)*Lc + kv0 + 64 + sg);
            }
        }
        f32x16 s0 = {}, s1 = {};
        __builtin_amdgcn_s_setprio(1);
        #pragma unroll
        for (int st = 0; st < 4; ++st) {
            const int slot = st*2 + g;
            bf16x8 ka0 = *(const bf16x8*)&Ks[cur][q31*64 + ((slot ^ (q31 & 7))*8)];
            bf16x8 ka1 = *(const bf16x8*)&Ks[cur][(32+q31)*64 + ((slot ^ (q31 & 7))*8)];
            s0 = __builtin_amdgcn_mfma_f32_32x32x16_bf16(ka0, qf[st], s0, 0,0,0);
            s1 = __builtin_amdgcn_mfma_f32_32x32x16_bf16(ka1, qf[st], s1, 0,0,0);
        }
        __builtin_amdgcn_s_setprio(0);
        float pmax = s0[0];
        #pragma unroll
        for (int r = 1; r < 16; ++r) pmax = fmaxf(pmax, s0[r]);
        #pragma unroll
        for (int r = 0; r < 16; ++r) pmax = fmaxf(pmax, s1[r]);
        pmax = fmaxf(pmax, __shfl_xor(pmax, 32, 64));
        if (!__all(pmax <= m_ + 8.f)) {
            const float mn = fmaxf(m_, pmax);
            const float al = __expf(m_ - mn);
            m_ = mn; l_ *= al;
            #pragma unroll
            for (int r = 0; r < 16; ++r) { o0[r] *= al; o1[r] *= al; }
        }
        #pragma unroll
        for (int r = 0; r < 16; ++r) {
            const float p0 = __expf(s0[r] - m_); s0[r] = p0; l_ += p0;
            const float p1 = __expf(s1[r] - m_); s1[r] = p1; l_ += p1;
        }
        __builtin_amdgcn_s_setprio(1);
        PV_STEP(0, s0); PV_STEP(1, s0); PV_STEP(2, s1); PV_STEP(3, s1);
        __builtin_amdgcn_s_setprio(0);
        __syncthreads();
        cur ^= 1;
    }

    const float lt = l_ + __shfl_xor(l_, 32, 64);
    if (g == 0) lred[w][q31] = lt;
    __syncthreads();
    const int b = bh >> 4, h = bh & 15;
    #pragma unroll
    for (int r = 0; r < 16; ++r) {
        const int ql = (r & 3) + 8*(r >> 2) + 4*g;
        const float inv = 1.f / lred[w][ql];
        const size_t prow = (size_t)b*LPAD + 1 + (q0 + ql);
        Opad[prow*Hc + h*64 + q31]      = f2b(o0[r]*inv);
        Opad[prow*Hc + h*64 + 32 + q31] = f2b(o1[r]*inv);
    }
}

extern "C" void kernel_launch(void* const* d_in, const int* in_sizes, int n_in,
                              void* d_out, int out_size, void* d_ws, size_t ws_size,
                              hipStream_t stream) {
    const float* x      = (const float*)d_in[0];
    const float* cond   = (const float*)d_in[1];
    const float* fcos   = (const float*)d_in[2];
    const float* fsin   = (const float*)d_in[3];
    const float* mod_w  = (const float*)d_in[4];
    const float* mod_b  = (const float*)d_in[5];
    const float* qkv_w  = (const float*)d_in[6];
    const float* qkv_b  = (const float*)d_in[7];
    const float* qn_w   = (const float*)d_in[8];
    const float* kn_w   = (const float*)d_in[9];
    const float* lin1_w = (const float*)d_in[10];
    const float* lin1_b = (const float*)d_in[11];
    const float* w1     = (const float*)d_in[12];
    const float* w2     = (const float*)d_in[13];
    const float* w3     = (const float*)d_in[14];
    float* out = (float*)d_out;
    char* wsb  = (char*)d_ws;

    float* mod  = (float*)(wsb + 0);                       // 48 KB
    u16* Wslot  = (u16*)(wsb + (1u<<20));                  // <=17.3 MiB, reused
    u16* Breg   = (u16*)(wsb + 19u*1024*1024);             // xn1 -> attn_pad
    u16* Creg   = (u16*)(wsb + 28u*1024*1024);             // qkvb -> h1a
    u16* Dreg   = (u16*)(wsb + 54u*1024*1024);             // Q,K,V,Vt -> xn2_pad
    u16* Ereg   = (u16*)(wsb + 88u*1024*1024);             // h1_pad

    u16* xn1  = Breg;
    u16* apad = Breg;
    u16* qkvb = Creg;
    u16* h1a  = Creg;       // reuse after qkvb is dead (post rope_rms)
    u16* Qb = Dreg;
    u16* Kb = Dreg + 4194304;
    u16* Vb = Dreg + 8388608;
    u16* Vt = Dreg + 12582912;
    u16* xn2p = Dreg;
    u16* h1p  = Ereg;

    dim3 blk(256), blkg(512);
    mod_kernel<<<dim3(H6/4, Bc), blk, 0, stream>>>(cond, mod_w, mod_b, mod);
    zero_pads<<<dim3((4*2816 + 255)/256), blk, 0, stream>>>(h1p, 2816);
    ln_mod_kernel<false><<<Mc, blk, 0, stream>>>(x, mod, 0, Hc, xn1);
    cvt_plain<<<dim3((3072*1024/4 + 255)/256), blk, 0, stream>>>(qkv_w, Wslot, 3072*1024);
    lgemm<1024,false,0,3072,1024,128><<<dim3(24,32), blkg, 0, stream>>>(
        xn1, Wslot, qkv_b, nullptr, nullptr, nullptr, 0, qkvb);
    zero_pads<<<dim3((4*1024 + 255)/256), blk, 0, stream>>>(apad, 1024);   // xn1 dead now
    rope_rms<<<dim3(Lc/4, 32), blk, 0, stream>>>(qkvb, qn_w, kn_w, fcos, fsin, Qb, Kb, Vb);
    vtrans<<<dim3(32, 32), blk, 0, stream>>>(Vb, Vt);
    attn_kernel<<<dim3(16, 32), blk, 0, stream>>>(Qb, Kb, Vt, apad);
    cvt_conv3<<<dim3((1024*256 + 255)/256), blk, 0, stream>>>(lin1_w, Wslot, 256, 1024*256);
    lgemm<3072,true,1,1024,1024,64><<<dim3(8,64), blkg, 0, stream>>>(
        apad, Wslot, lin1_b, x, nullptr, mod, 2*Hc, (void*)out);
    zero_pads<<<dim3((4*1024 + 255)/256), blk, 0, stream>>>(xn2p, 1024);   // Q..Vt dead now
    ln_mod_kernel<true><<<Mc, blk, 0, stream>>>(out, mod, 3*Hc, 4*Hc, xn2p);
    cvt_conv3<<<dim3((2816*256 + 255)/256), blk, 0, stream>>>(w1, Wslot, 256, 2816*256);
    lgemm<3072,true,2,2816,1024,128><<<dim3(22,32), blkg, 0, stream>>>(
        xn2p, Wslot, nullptr, nullptr, nullptr, nullptr, 0, h1a);
    cvt_conv3<<<dim3((2816*256 + 255)/256), blk, 0, stream>>>(w3, Wslot, 256, 2816*256);
    lgemm<3072,true,3,2816,1024,128><<<dim3(22,32), blkg, 0, stream>>>(
        xn2p, Wslot, nullptr, nullptr, h1a, nullptr, 0, h1p);
    cvt_conv3<<<dim3((1024*704 + 255)/256), blk, 0, stream>>>(w2, Wslot, 704, 1024*704);
    lgemm<8448,true,1,1024,2816,64><<<dim3(8,64), blkg, 0, stream>>>(
        h1p, Wslot, nullptr, out, nullptr, mod, 5*Hc, (void*)out);
    (void)in_sizes; (void)n_in; (void)out_size; (void)ws_size;
}

// Round 18
// 441.411 us; speedup vs baseline: 1.0748x; 1.0189x over previous
//
#include <hip/hip_runtime.h>
#include <math.h>

typedef unsigned short u16;
typedef __attribute__((ext_vector_type(8))) short bf16x8;   // 8 bf16 (4 VGPRs)
typedef __attribute__((ext_vector_type(4))) float f32x4;
typedef __attribute__((ext_vector_type(16))) float f32x16;

#define Bc   2
#define Lc   2048
#define Hc   1024
#define H6   6144
#define Mc   4096          // B*L
#define LPAD 2050          // padded rows per batch (1 zero row each side)

__device__ __forceinline__ u16 f2b(float f) {
    union { float f; unsigned u; } x; x.f = f;
    unsigned r = x.u + 0x7fffu + ((x.u >> 16) & 1u);
    return (u16)(r >> 16);
}
__device__ __forceinline__ float b2f(u16 h) {
    union { unsigned u; float f; } x; x.u = ((unsigned)h) << 16;
    return x.f;
}
__device__ __forceinline__ void async16(u16* lds, const u16* g) {
    __builtin_amdgcn_global_load_lds((const __attribute__((address_space(1))) void*)g,
                                     (__attribute__((address_space(3))) void*)lds, 16, 0, 0);
}
template<int N> __device__ __forceinline__ void waitcnt_vm() {
    static_assert(N==0 || N==3 || N==4, "literal vmcnt");
    if constexpr (N==0)      asm volatile("s_waitcnt vmcnt(0)" ::: "memory");
    else if constexpr (N==3) asm volatile("s_waitcnt vmcnt(3)" ::: "memory");
    else                     asm volatile("s_waitcnt vmcnt(4)" ::: "memory");
}
__device__ __forceinline__ float wave_reduce_sum(float v) {
    #pragma unroll
    for (int m = 1; m < 64; m <<= 1) v += __shfl_xor(v, m, 64);
    return v;
}

// ---------------- mod = silu(cond) @ mod_w.T + mod_b (wave per output) ----------
__global__ void mod_kernel(const float* __restrict__ cond, const float* __restrict__ mw,
                           const float* __restrict__ mb, float* __restrict__ mod) {
    __shared__ float sc[Hc];
    int b = blockIdx.y;
    int tid = threadIdx.x;
    for (int i = tid; i < Hc; i += 256) {
        float c = cond[b*Hc + i];
        sc[i] = c / (1.f + __expf(-c));
    }
    __syncthreads();
    int w = tid >> 6, lane = tid & 63;
    int j = blockIdx.x*4 + w;
    const float4* wr = (const float4*)(mw + (size_t)j*Hc);
    const float4* s4 = (const float4*)sc;
    float acc = 0.f;
    #pragma unroll
    for (int i = 0; i < 4; ++i) {
        float4 v = wr[lane + i*64];
        float4 s = s4[lane + i*64];
        acc += v.x*s.x + v.y*s.y + v.z*s.z + v.w*s.w;
    }
    acc = wave_reduce_sum(acc);
    if (lane == 0) mod[b*H6 + j] = acc + mb[j];
}

// ---------------- layernorm(x)*(1+scale)+shift -> bf16 (optionally padded) ------
template<bool PAD>
__global__ void ln_mod_kernel(const float* __restrict__ x, const float* __restrict__ mod,
                              int shoff, int scoff, u16* __restrict__ out) {
    int m = blockIdx.x;
    int b = m >> 11;
    int tid = threadIdx.x;
    float4 v = ((const float4*)(x + (size_t)m*Hc))[tid];
    float s1 = v.x+v.y+v.z+v.w;
    float s2 = v.x*v.x + v.y*v.y + v.z*v.z + v.w*v.w;
    s1 = wave_reduce_sum(s1); s2 = wave_reduce_sum(s2);
    __shared__ float red[8];
    int wid = tid >> 6, lane = tid & 63;
    if (lane == 0) { red[wid] = s1; red[4+wid] = s2; }
    __syncthreads();
    s1 = red[0]+red[1]+red[2]+red[3];
    s2 = red[4]+red[5]+red[6]+red[7];
    float mean = s1 * (1.f/Hc);
    float var  = s2 * (1.f/Hc) - mean*mean;
    float inv  = rsqrtf(var + 1e-5f);
    float4 shv = ((const float4*)(mod + b*H6 + shoff))[tid];
    float4 scv = ((const float4*)(mod + b*H6 + scoff))[tid];
    ushort4 o;
    o.x = f2b((v.x-mean)*inv*(1.f+scv.x)+shv.x);
    o.y = f2b((v.y-mean)*inv*(1.f+scv.y)+shv.y);
    o.z = f2b((v.z-mean)*inv*(1.f+scv.z)+shv.z);
    o.w = f2b((v.w-mean)*inv*(1.f+scv.w)+shv.w);
    size_t row = PAD ? ((size_t)b*LPAD + 1 + (m & 2047)) : (size_t)m;
    ((ushort4*)(out + row*Hc))[tid] = o;
}

// ---------------- weight converters ----------------
__global__ void cvt_plain(const float* __restrict__ src, u16* __restrict__ dst, int n) {
    int i = (blockIdx.x*256 + threadIdx.x)*4;
    if (i < n) {
        float4 v = *(const float4*)(src + i);
        ushort4 o; o.x=f2b(v.x); o.y=f2b(v.y); o.z=f2b(v.z); o.w=f2b(v.w);
        *(ushort4*)(dst + i) = o;
    }
}
// [N][K][3] f32 -> [N][3K] bf16 (K-linearized conv weights), 4 k per thread
__global__ void cvt_conv3(const float* __restrict__ src, u16* __restrict__ dst,
                          int K4, int total) {
    int i = blockIdx.x*256 + threadIdx.x;
    if (i >= total) return;
    int n = i / K4, k4 = (i - n*K4)*4;
    int Kf = K4*4;
    const float4* s4 = (const float4*)(src + ((size_t)n*Kf + k4)*3);
    float4 a = s4[0], b = s4[1], c = s4[2];
    ushort4 t0 = {f2b(a.x), f2b(a.w), f2b(b.z), f2b(c.y)};
    ushort4 t1 = {f2b(a.y), f2b(b.x), f2b(b.w), f2b(c.z)};
    ushort4 t2 = {f2b(a.z), f2b(b.y), f2b(c.x), f2b(c.w)};
    u16* drow = dst + (size_t)n*3*Kf + k4;
    *(ushort4*)(drow)        = t0;
    *(ushort4*)(drow + Kf)   = t1;
    *(ushort4*)(drow + 2*Kf) = t2;
}
__global__ void zero_pads(u16* __restrict__ p, int Kw) {
    int t = blockIdx.x*256 + threadIdx.x;
    if (t >= 4*Kw) return;
    int rr = t / Kw, c = t - rr*Kw;
    int row = (rr >> 1)*2050 + (rr & 1)*2049;   // 0, 2049, 2050, 4099
    p[(size_t)row*Kw + c] = 0;
}

// ---------------- K-linearized MFMA GEMM, 8-wave split-K, counted-vmcnt --------
// C[M,N] = A_eff[M,KEFF] @ W[N,KEFF]^T.  A_eff row m = &Apad[(m-1)*K], stride K.
// R18: R17 (=R14 best, 450us) + 2D XCD map for K=1024 GEMMs: 4(m)x2(n) chunks
// halve W re-streaming (8x -> 4x NK) while the per-XCD A band (1024 rows x 2KB
// = 2MB) stays L2-resident. w2 (K=2816: 4-band = 5.8MB > L2) keeps the proven
// 8-band map. Split-K waves (R14); 2-deep counted-vmcnt (R11).
// EPI: 0 = +bias->bf16 ; 1 = prev+gate*(acc+bias)->f32 ; 2 = plain bf16 ;
//      3 = silu(other)*acc -> bf16 padded
template<int KEFF, bool PADDED, int EPI, int N, int K, int BM>
__global__ __launch_bounds__(512, 2)
void lgemm(const u16* __restrict__ A, const u16* __restrict__ W,
           const float* __restrict__ bias, const float* __restrict__ prev,
           const u16* __restrict__ other, const float* __restrict__ mod,
           int gate_off, void* __restrict__ Cout)
{
    constexpr int MT  = Mc/BM;
    constexpr int NT  = N/128;
    constexpr int FI  = 4;                     // 64 rows per wave
    constexpr int FJ  = (BM == 128) ? 4 : 2;   // 64 / 32 cols per wave
    constexpr int NPH = KEFF/64;
    constexpr int ACH = BM/64;                 // A stage rounds per lane (2 or 1)
    constexpr int LPS = ACH + 2;               // loads/lane/stage (4 or 3)
    __shared__ __align__(16) u16 ldsbuf[2*BM*64 + 2*128*64];

    const int tid = threadIdx.x;
    const int w = tid >> 6, lane = tid & 63;
    const int wk = w >> 2;                                 // K-half owner
    const int wm = (BM == 128) ? ((w >> 1) & 1) : 0;
    const int wn = (BM == 128) ? (w & 1) : (w & 3);
    const int wcol = wn * (128/((BM == 128) ? 2 : 4));     // 64 or 32

    const int orig = blockIdx.x + gridDim.x * blockIdx.y;
    const int xcd = orig & 7, li = orig >> 3;
    int tm, tn;
    if constexpr (K == 1024) {
        // 2D XCD chunks 4(m) x 2(n); n-fastest within chunk
        constexpr int cNT = NT/2;
        tm = (xcd >> 1)*(MT/4) + li/cNT;
        tn = (xcd & 1)*cNT + li % cNT;
    } else {
        tm = xcd*(MT/8) + li/NT;               // XCD-private row band
        tn = li % NT;                          // n-fastest within band
    }
    const int m0 = tm*BM, n0 = tn*128;

    const u16* Ab = PADDED ? A + ((size_t)(m0 >> 11)*LPAD + (m0 & 2047))*K
                           : A + (size_t)m0*K;
    const u16* Wb = W + (size_t)n0*KEFF;

    const int lr  = lane >> 3;                 // row within 8-row chunk
    const int lsw = ((lane & 7) ^ lr) * 8;     // pre-swizzled source slot

    const int frow = lane & 15, fsl = lane >> 4;
    const int kslot = wk*4 + fsl;              // this wave's K-half slots

    f32x4 acc[FI][FJ] = {};

#define ASB(buf) (ldsbuf + (buf)*BM*64)
#define WSB(buf) (ldsbuf + 2*BM*64 + (buf)*128*64)
#define STAGE(t, buf) do {                                                        \
    const int k0_ = (t)*64;                                                       \
    _Pragma("unroll")                                                             \
    for (int i_ = 0; i_ < ACH; ++i_)                                              \
        async16(ASB(buf) + (w + i_*8)*512,                                        \
                Ab + (size_t)((w + i_*8)*8 + lr)*K + k0_ + lsw);                  \
    _Pragma("unroll")                                                             \
    for (int i_ = 0; i_ < 2; ++i_)                                                \
        async16(WSB(buf) + (w + i_*8)*512,                                        \
                Wb + (size_t)((w + i_*8)*8 + lr)*KEFF + k0_ + lsw);               \
} while (0)

    STAGE(0, 0);
    STAGE(1, 1);

    for (int t = 0; t < NPH; ++t) {
        const int cur = t & 1;
        if (t < NPH - 1) waitcnt_vm<LPS>(); else waitcnt_vm<0>();
        __builtin_amdgcn_sched_barrier(0);
        __builtin_amdgcn_s_barrier();              // all waves: cur loads landed
        __builtin_amdgcn_sched_barrier(0);
        bf16x8 a[FI], b[FJ];
        #pragma unroll
        for (int f = 0; f < FI; ++f) {
            const int ar = wm*64 + f*16 + frow;
            a[f] = *(const bf16x8*)&ASB(cur)[ar*64 + ((kslot ^ (ar & 7))*8)];
        }
        #pragma unroll
        for (int f = 0; f < FJ; ++f) {
            const int br = wcol + f*16 + frow;
            b[f] = *(const bf16x8*)&WSB(cur)[br*64 + ((kslot ^ (br & 7))*8)];
        }
        __builtin_amdgcn_sched_barrier(0);
        asm volatile("s_waitcnt lgkmcnt(0)" ::: "memory");
        __builtin_amdgcn_sched_barrier(0);
        __builtin_amdgcn_s_barrier();              // all waves done reading cur
        __builtin_amdgcn_sched_barrier(0);
        if (t + 2 < NPH) STAGE(t + 2, cur);        // overwrite cur for t+2
        __builtin_amdgcn_sched_barrier(0);
        __builtin_amdgcn_s_setprio(1);
        #pragma unroll
        for (int fi = 0; fi < FI; ++fi)
            #pragma unroll
            for (int fj = 0; fj < FJ; ++fj)
                acc[fi][fj] = __builtin_amdgcn_mfma_f32_16x16x32_bf16(
                    a[fi], b[fj], acc[fi][fj], 0, 0, 0);
        __builtin_amdgcn_s_setprio(0);
    }
#undef STAGE

    // ---- split-K merge: wk=1 waves dump acc into (dead) staging LDS ----
    constexpr int PR = FI*FJ*64;               // f32x4 slots per pair
    f32x4* mrg = (f32x4*)ldsbuf;
    __syncthreads();
    if (wk == 1) {
        #pragma unroll
        for (int fi = 0; fi < FI; ++fi)
            #pragma unroll
            for (int fj = 0; fj < FJ; ++fj)
                mrg[(w & 3)*PR + (fi*FJ + fj)*64 + lane] = acc[fi][fj];
    }
    __syncthreads();
    if (wk == 1) return;
    #pragma unroll
    for (int fi = 0; fi < FI; ++fi)
        #pragma unroll
        for (int fj = 0; fj < FJ; ++fj)
            acc[fi][fj] += mrg[(w & 3)*PR + (fi*FJ + fj)*64 + lane];

    // epilogue: D row=(lane>>4)*4+reg, col=lane&15  [verified m89]
    #pragma unroll
    for (int fi = 0; fi < FI; ++fi) {
        #pragma unroll
        for (int i = 0; i < 4; ++i) {
            const int gm = m0 + wm*64 + fi*16 + (lane >> 4)*4 + i;
            const int bb = gm >> 11;
            #pragma unroll
            for (int fj = 0; fj < FJ; ++fj) {
                const int col = n0 + wcol + fj*16 + frow;
                float r = acc[fi][fj][i];
                if (EPI == 0) {
                    ((u16*)Cout)[(size_t)gm*N + col] = f2b(r + bias[col]);
                } else if (EPI == 1) {
                    if (bias) r += bias[col];
                    const float g = mod[bb*H6 + gate_off + col];
                    ((float*)Cout)[(size_t)gm*N + col] =
                        prev[(size_t)gm*N + col] + g*r;
                } else if (EPI == 2) {
                    ((u16*)Cout)[(size_t)gm*N + col] = f2b(r);
                } else {
                    const float h = b2f(other[(size_t)gm*N + col]);
                    const float v = h / (1.f + __expf(-h)) * r;
                    ((u16*)Cout)[((size_t)bb*LPAD + 1 + (gm & 2047))*N + col] = f2b(v);
                }
            }
        }
    }
#undef ASB
#undef WSB
}

// ---------------- RMSNorm + RoPE + split qkv (bf16 in/out; Q pre-scaled) --------
__global__ void rope_rms(const u16* __restrict__ qkv,
                         const float* __restrict__ qn_w, const float* __restrict__ kn_w,
                         const float* __restrict__ fcos, const float* __restrict__ fsin,
                         u16* __restrict__ Q, u16* __restrict__ K, u16* __restrict__ V) {
    int bh = blockIdx.y;
    int l  = blockIdx.x*4 + (threadIdx.x >> 6);
    int d  = threadIdx.x & 63;
    int b  = bh >> 4, h = bh & 15;
    size_t base = ((size_t)(b*Lc + l))*3072 + (size_t)(h*64 + d)*3;
    float qv = b2f(qkv[base + 0]);
    float kv = b2f(qkv[base + 1]);
    float vv = b2f(qkv[base + 2]);
    float qs = wave_reduce_sum(qv*qv) * (1.f/64.f);
    float ks = wave_reduce_sum(kv*kv) * (1.f/64.f);
    float qn = qv * rsqrtf(qs + 1e-6f) * qn_w[d];
    float kn = kv * rsqrtf(ks + 1e-6f) * kn_w[d];
    float c = fcos[l*64 + d], s = fsin[l*64 + d];
    float qp = __shfl_xor(qn, 1, 64);
    float kp = __shfl_xor(kn, 1, 64);
    float qr = (d & 1) ? qp : -qp;
    float kr = (d & 1) ? kp : -kp;
    size_t o = ((size_t)bh*Lc + l)*64 + d;
    Q[o] = f2b((qn*c + qr*s) * 0.125f);     // fold 1/sqrt(D) into Q
    K[o] = f2b(kn*c + kr*s);
    V[o] = f2b(vv);
}

// ---------------- V transpose: [bh][l][64] -> [bh][64][l] ----------------
__global__ void vtrans(const u16* __restrict__ V, u16* __restrict__ Vt) {
    __shared__ u16 t[64][65];
    int bh = blockIdx.y, l0 = blockIdx.x*64;
    int tid = threadIdx.x;
    #pragma unroll
    for (int p = 0; p < 16; ++p) {
        int idx = p*256 + tid; int r = idx >> 6, c = idx & 63;
        t[r][c] = V[((size_t)bh*Lc + l0 + r)*64 + c];
    }
    __syncthreads();
    #pragma unroll
    for (int p = 0; p < 16; ++p) {
        int idx = p*256 + tid; int d = idx >> 6, c = idx & 63;
        Vt[((size_t)bh*64 + d)*Lc + l0 + c] = t[c][d];
    }
}

// ---------------- flash attention: 32x32 MFMA, in-register softmax ----------
#define PV_STEP(c, SV) do {                                                        \
    unsigned cA,cB,cC,cD;                                                          \
    asm("v_cvt_pk_bf16_f32 %0,%1,%2" : "=v"(cA) : "v"(SV[((c)&1)*8+0]), "v"(SV[((c)&1)*8+1])); \
    asm("v_cvt_pk_bf16_f32 %0,%1,%2" : "=v"(cB) : "v"(SV[((c)&1)*8+2]), "v"(SV[((c)&1)*8+3])); \
    asm("v_cvt_pk_bf16_f32 %0,%1,%2" : "=v"(cC) : "v"(SV[((c)&1)*8+4]), "v"(SV[((c)&1)*8+5])); \
    asm("v_cvt_pk_bf16_f32 %0,%1,%2" : "=v"(cD) : "v"(SV[((c)&1)*8+6]), "v"(SV[((c)&1)*8+7])); \
    asm("v_permlane32_swap_b32 %0, %1" : "+v"(cA), "+v"(cC));                      \
    asm("v_permlane32_swap_b32 %0, %1" : "+v"(cB), "+v"(cD));                      \
    union { unsigned u[4]; bf16x8 v; } pa_;                                        \
    pa_.u[0]=cA; pa_.u[1]=cB; pa_.u[2]=cC; pa_.u[3]=cD;                            \
    const int slot_ = (c)*2 + g;                                                   \
    bf16x8 vA = *(const bf16x8*)&Vs[cur][q31*64 + ((slot_ ^ (q31 & 7))*8)];        \
    bf16x8 vB = *(const bf16x8*)&Vs[cur][(32+q31)*64 + ((slot_ ^ (q31 & 7))*8)];   \
    o0 = __builtin_amdgcn_mfma_f32_32x32x16_bf16(pa_.v, vA, o0, 0,0,0);            \
    o1 = __builtin_amdgcn_mfma_f32_32x32x16_bf16(pa_.v, vB, o1, 0,0,0);            \
} while(0)

__global__ __launch_bounds__(256, 2)
void attn_kernel(const u16* __restrict__ Q, const u16* __restrict__ K,
                 const u16* __restrict__ Vt, u16* __restrict__ Opad)
{
    __shared__ u16 Ks[2][4096];
    __shared__ u16 Vs[2][4096];
    __shared__ float lred[4][32];
    const int tid = threadIdx.x;
    const int w = tid >> 6, lane = tid & 63;
    const int q31 = lane & 31, g = lane >> 5;
    const int bh = blockIdx.y;
    const int q0 = blockIdx.x*128 + w*32;
    const u16* Qb = Q  + (size_t)bh*Lc*64;
    const u16* Kb = K  + (size_t)bh*Lc*64;
    const u16* Vb = Vt + (size_t)bh*Lc*64;   // [64 d][2048 kv]

    bf16x8 qf[4];
    #pragma unroll
    for (int st = 0; st < 4; ++st)
        qf[st] = *(const bf16x8*)&Qb[(size_t)(q0 + q31)*64 + st*16 + g*8];

    f32x16 o0 = {}, o1 = {};
    float m_ = -1e30f, l_ = 0.f;

    const int sr = lane >> 3;
    const int sg = ((lane & 7) ^ sr) * 8;

    #pragma unroll
    for (int i = 0; i < 2; ++i) {
        const int c = w + i*4;
        async16(&Ks[0][c*512], Kb + (size_t)(c*8 + sr)*64 + sg);
        async16(&Vs[0][c*512], Vb + (size_t)(c*8 + sr)*Lc + sg);
    }
    __syncthreads();

    int cur = 0;
    for (int kv0 = 0; kv0 < Lc; kv0 += 64) {
        if (kv0 + 64 < Lc) {
            #pragma unroll
            for (int i = 0; i < 2; ++i) {
                const int c = w + i*4;
                async16(&Ks[cur^1][c*512], Kb + (size_t)(kv0 + 64 + c*8 + sr)*64 + sg);
                async16(&Vs[cur^1][c*512], Vb + (size_t)(c*8 + sr)*Lc + kv0 + 64 + sg);
            }
        }
        f32x16 s0 = {}, s1 = {};
        __builtin_amdgcn_s_setprio(1);
        #pragma unroll
        for (int st = 0; st < 4; ++st) {
            const int slot = st*2 + g;
            bf16x8 ka0 = *(const bf16x8*)&Ks[cur][q31*64 + ((slot ^ (q31 & 7))*8)];
            bf16x8 ka1 = *(const bf16x8*)&Ks[cur][(32+q31)*64 + ((slot ^ (q31 & 7))*8)];
            s0 = __builtin_amdgcn_mfma_f32_32x32x16_bf16(ka0, qf[st], s0, 0,0,0);
            s1 = __builtin_amdgcn_mfma_f32_32x32x16_bf16(ka1, qf[st], s1, 0,0,0);
        }
        __builtin_amdgcn_s_setprio(0);
        float pmax = s0[0];
        #pragma unroll
        for (int r = 1; r < 16; ++r) pmax = fmaxf(pmax, s0[r]);
        #pragma unroll
        for (int r = 0; r < 16; ++r) pmax = fmaxf(pmax, s1[r]);
        pmax = fmaxf(pmax, __shfl_xor(pmax, 32, 64));
        if (!__all(pmax <= m_ + 8.f)) {
            const float mn = fmaxf(m_, pmax);
            const float al = __expf(m_ - mn);
            m_ = mn; l_ *= al;
            #pragma unroll
            for (int r = 0; r < 16; ++r) { o0[r] *= al; o1[r] *= al; }
        }
        #pragma unroll
        for (int r = 0; r < 16; ++r) {
            const float p0 = __expf(s0[r] - m_); s0[r] = p0; l_ += p0;
            const float p1 = __expf(s1[r] - m_); s1[r] = p1; l_ += p1;
        }
        __builtin_amdgcn_s_setprio(1);
        PV_STEP(0, s0); PV_STEP(1, s0); PV_STEP(2, s1); PV_STEP(3, s1);
        __builtin_amdgcn_s_setprio(0);
        __syncthreads();
        cur ^= 1;
    }

    const float lt = l_ + __shfl_xor(l_, 32, 64);
    if (g == 0) lred[w][q31] = lt;
    __syncthreads();
    const int b = bh >> 4, h = bh & 15;
    #pragma unroll
    for (int r = 0; r < 16; ++r) {
        const int ql = (r & 3) + 8*(r >> 2) + 4*g;
        const float inv = 1.f / lred[w][ql];
        const size_t prow = (size_t)b*LPAD + 1 + (q0 + ql);
        Opad[prow*Hc + h*64 + q31]      = f2b(o0[r]*inv);
        Opad[prow*Hc + h*64 + 32 + q31] = f2b(o1[r]*inv);
    }
}

extern "C" void kernel_launch(void* const* d_in, const int* in_sizes, int n_in,
                              void* d_out, int out_size, void* d_ws, size_t ws_size,
                              hipStream_t stream) {
    const float* x      = (const float*)d_in[0];
    const float* cond   = (const float*)d_in[1];
    const float* fcos   = (const float*)d_in[2];
    const float* fsin   = (const float*)d_in[3];
    const float* mod_w  = (const float*)d_in[4];
    const float* mod_b  = (const float*)d_in[5];
    const float* qkv_w  = (const float*)d_in[6];
    const float* qkv_b  = (const float*)d_in[7];
    const float* qn_w   = (const float*)d_in[8];
    const float* kn_w   = (const float*)d_in[9];
    const float* lin1_w = (const float*)d_in[10];
    const float* lin1_b = (const float*)d_in[11];
    const float* w1     = (const float*)d_in[12];
    const float* w2     = (const float*)d_in[13];
    const float* w3     = (const float*)d_in[14];
    float* out = (float*)d_out;
    char* wsb  = (char*)d_ws;

    float* mod  = (float*)(wsb + 0);                       // 48 KB
    u16* Wslot  = (u16*)(wsb + (1u<<20));                  // <=17.3 MiB, reused
    u16* Breg   = (u16*)(wsb + 19u*1024*1024);             // xn1 -> attn_pad
    u16* Creg   = (u16*)(wsb + 28u*1024*1024);             // qkvb -> h1a
    u16* Dreg   = (u16*)(wsb + 54u*1024*1024);             // Q,K,V,Vt -> xn2_pad
    u16* Ereg   = (u16*)(wsb + 88u*1024*1024);             // h1_pad

    u16* xn1  = Breg;
    u16* apad = Breg;
    u16* qkvb = Creg;
    u16* h1a  = Creg;       // reuse after qkvb is dead (post rope_rms)
    u16* Qb = Dreg;
    u16* Kb = Dreg + 4194304;
    u16* Vb = Dreg + 8388608;
    u16* Vt = Dreg + 12582912;
    u16* xn2p = Dreg;
    u16* h1p  = Ereg;

    dim3 blk(256), blkg(512);
    mod_kernel<<<dim3(H6/4, Bc), blk, 0, stream>>>(cond, mod_w, mod_b, mod);
    zero_pads<<<dim3((4*2816 + 255)/256), blk, 0, stream>>>(h1p, 2816);
    ln_mod_kernel<false><<<Mc, blk, 0, stream>>>(x, mod, 0, Hc, xn1);
    cvt_plain<<<dim3((3072*1024/4 + 255)/256), blk, 0, stream>>>(qkv_w, Wslot, 3072*1024);
    lgemm<1024,false,0,3072,1024,128><<<dim3(24,32), blkg, 0, stream>>>(
        xn1, Wslot, qkv_b, nullptr, nullptr, nullptr, 0, qkvb);
    zero_pads<<<dim3((4*1024 + 255)/256), blk, 0, stream>>>(apad, 1024);   // xn1 dead now
    rope_rms<<<dim3(Lc/4, 32), blk, 0, stream>>>(qkvb, qn_w, kn_w, fcos, fsin, Qb, Kb, Vb);
    vtrans<<<dim3(32, 32), blk, 0, stream>>>(Vb, Vt);
    attn_kernel<<<dim3(16, 32), blk, 0, stream>>>(Qb, Kb, Vt, apad);
    cvt_conv3<<<dim3((1024*256 + 255)/256), blk, 0, stream>>>(lin1_w, Wslot, 256, 1024*256);
    lgemm<3072,true,1,1024,1024,64><<<dim3(8,64), blkg, 0, stream>>>(
        apad, Wslot, lin1_b, x, nullptr, mod, 2*Hc, (void*)out);
    zero_pads<<<dim3((4*1024 + 255)/256), blk, 0, stream>>>(xn2p, 1024);   // Q..Vt dead now
    ln_mod_kernel<true><<<Mc, blk, 0, stream>>>(out, mod, 3*Hc, 4*Hc, xn2p);
    cvt_conv3<<<dim3((2816*256 + 255)/256), blk, 0, stream>>>(w1, Wslot, 256, 2816*256);
    lgemm<3072,true,2,2816,1024,128><<<dim3(22,32), blkg, 0, stream>>>(
        xn2p, Wslot, nullptr, nullptr, nullptr, nullptr, 0, h1a);
    cvt_conv3<<<dim3((2816*256 + 255)/256), blk, 0, stream>>>(w3, Wslot, 256, 2816*256);
    lgemm<3072,true,3,2816,1024,128><<<dim3(22,32), blkg, 0, stream>>>(
        xn2p, Wslot, nullptr, nullptr, h1a, nullptr, 0, h1p);
    cvt_conv3<<<dim3((1024*704 + 255)/256), blk, 0, stream>>>(w2, Wslot, 704, 1024*704);
    lgemm<8448,true,1,1024,2816,64><<<dim3(8,64), blkg, 0, stream>>>(
        h1p, Wslot, nullptr, out, nullptr, mod, 5*Hc, (void*)out);
    (void)in_sizes; (void)n_in; (void)out_size; (void)ws_size;
}